// Round 19
// baseline (361.469 us; speedup 1.0000x reference)
//
#include <hip/hip_runtime.h>
#include <cfloat>
#include <cmath>
#include <stdint.h>

#define NROWS 32768
#define DIM   256
#define KC    1024
#define MARGIN 0.125f

typedef short bf16x8 __attribute__((ext_vector_type(8)));
typedef float f32x4  __attribute__((ext_vector_type(4)));
typedef float f32x2  __attribute__((ext_vector_type(2)));

__device__ inline unsigned short f2bf(float f) {
    unsigned u = __float_as_uint(f);
    u = (u + 0x7fffu + ((u >> 16) & 1u)) >> 16;   // RNE
    return (unsigned short)u;
}

// ---------- prep_wnorm: pack w (hi bf16) + transpose + column norms ----------
// 64 blocks x 512 threads, one 16-col group (ctg) per block.
__global__ __launch_bounds__(512) void prep_wnorm(const float* __restrict__ w,
                                                  uint4* __restrict__ wph,
                                                  float* __restrict__ wT,
                                                  double* __restrict__ wnorm64,
                                                  float* __restrict__ wnormf) {
    const int tl = threadIdx.x;
    const int ctg = blockIdx.x;
    const int t = ctg * 512 + tl;
    const int l = tl & 63;
    const int ks = (tl >> 6) & 7;
    const int c = ctg * 16 + (l & 15);
    const int kbase = ks * 32 + ((l >> 4) << 3);
    union { unsigned short u[8]; uint4 v; } H;
    double s = 0.0;
#pragma unroll
    for (int j = 0; j < 8; ++j) {
        float v = w[(size_t)(kbase + j) * KC + c];
        H.u[j] = f2bf(v);
        wT[(size_t)c * DIM + kbase + j] = v;
        s = fma((double)v, (double)v, s);
    }
    wph[t] = H.v;
    s += __shfl_xor(s, 16);
    s += __shfl_xor(s, 32);
    __shared__ double part[8][16];
    if (l < 16) part[ks][l] = s;
    __syncthreads();
    if (tl < 16) {
        double tot = 0.0;
#pragma unroll
        for (int i = 0; i < 8; ++i) tot += part[i][tl];
        wnorm64[ctg * 16 + tl] = tot;
        wnormf[ctg * 16 + tl] = (float)tot;
    }
}

// ---------- fused kernel: bf16 screen (R16) + ticket-merged final ----------
// block = (rowtile rt = bid>>1 [64 rows], part p = bid&1 [512 cols]).
// 16 staging groups of 32 cols (16KB), 2x16KB LDS double buffer, (256,4).
// After candidate write: atomicAdd ticket[rt]; the SECOND finisher merges both
// parts' candidates and runs the full epilogue for its 64 rows — overlapped
// with other blocks still screening (same stall-shadow mechanism as zero-fill).
__global__ __launch_bounds__(256, 4) void vq_fused(
    const float* __restrict__ x,
    const char* __restrict__ wph,
    const float* __restrict__ wT,
    const double* __restrict__ wnorm64, const float* __restrict__ wnormf,
    int* __restrict__ cand, int* __restrict__ ticket,
    float* __restrict__ out_q, float* __restrict__ out_idx, float* __restrict__ out_enc,
    int* __restrict__ counts, double* __restrict__ loss_sum)
{
    __shared__ char ldsbuf[32768];
    __shared__ int sh_tick;
    __shared__ double wsum[4];

    const int t = threadIdx.x;
    const int l = t & 63;
    const int wv = t >> 6;
    const int p = blockIdx.x & 1;
    const int rt = blockIdx.x >> 1;
    const int r0 = rt * 64 + wv * 16;
    const size_t pbase = (size_t)p * 262144;   // part offset into wph (bytes)

    // ---- A fragments: 16 rows x 256 k, hi bf16 ----
    bf16x8 ah[8];
    {
        const float* xb = x + (size_t)(r0 + (l & 15)) * DIM + ((l >> 4) << 3);
#pragma unroll
        for (int ks = 0; ks < 8; ++ks) {
            float4 p0 = *(const float4*)(xb + ks * 32);
            float4 p1 = *(const float4*)(xb + ks * 32 + 4);
            float f[8] = {p0.x, p0.y, p0.z, p0.w, p1.x, p1.y, p1.z, p1.w};
            union { unsigned short u[8]; bf16x8 v; } H;
#pragma unroll
            for (int j = 0; j < 8; ++j) H.u[j] = f2bf(f[j]);
            ah[ks] = H.v;
        }
    }

    float tv0[4], tv1[4], tv2[4];
    int   tk0[4], tk1[4], tk2[4];
#pragma unroll
    for (int r = 0; r < 4; ++r) { tv0[r] = tv1[r] = tv2[r] = FLT_MAX; tk0[r] = tk1[r] = tk2[r] = 0; }

    // ---- K-loop: 16 groups of 32 cols, double-buffered ----
    {
        const char* g0 = wph + pbase + wv * 4096 + l * 16;
        char* lp0 = ldsbuf + wv * 4096 + l * 16;
#pragma unroll
        for (int i = 0; i < 4; ++i)
            __builtin_amdgcn_global_load_lds(
                (const __attribute__((address_space(1))) void*)(g0 + i * 1024),
                (__attribute__((address_space(3))) void*)(lp0 + i * 1024), 16, 0, 0);
    }
    __syncthreads();

    int cur = 0;
    for (int g = 0; g < 16; ++g) {
        if (g + 1 < 16) {
            const char* gp = wph + pbase + (size_t)(g + 1) * 16384 + wv * 4096 + l * 16;
            char* lp = ldsbuf + (cur ^ 1) * 16384 + wv * 4096 + l * 16;
#pragma unroll
            for (int i = 0; i < 4; ++i)
                __builtin_amdgcn_global_load_lds(
                    (const __attribute__((address_space(1))) void*)(gp + i * 1024),
                    (__attribute__((address_space(3))) void*)(lp + i * 1024), 16, 0, 0);
        }

        // enc zero-fill in the load-stall shadow: one row x 512 cols per iter
        {
            const int zrow = r0 + g;
            f32x2* er2 = (f32x2*)(out_enc + (size_t)zrow * KC + p * 512);
            f32x2 z = {0.f, 0.f};
#pragma unroll
            for (int i = 0; i < 4; ++i)
                __builtin_nontemporal_store(z, er2 + i * 64 + l);
        }

        f32x4 acc[2];
#pragma unroll
        for (int ct = 0; ct < 2; ++ct) acc[ct] = (f32x4){0.f, 0.f, 0.f, 0.f};

#pragma unroll
        for (int ks = 0; ks < 8; ++ks) {
#pragma unroll
            for (int ct = 0; ct < 2; ++ct) {
                bf16x8 bh = *(const bf16x8*)(ldsbuf + cur * 16384 + ((ct * 8 + ks) * 64 + l) * 16);
                acc[ct] = __builtin_amdgcn_mfma_f32_16x16x32_bf16(ah[ks], bh, acc[ct], 0, 0, 0);
            }
        }

#pragma unroll
        for (int ct = 0; ct < 2; ++ct) {
            const int k = (p * 32 + g * 2 + ct) * 16 + (l & 15);
            const float wn = wnormf[k];
#pragma unroll
            for (int r = 0; r < 4; ++r) {
                float s = wn - 2.0f * acc[ct][r];
                if (s < tv2[r]) {
                    if (s < tv1[r]) {
                        tv2[r] = tv1[r]; tk2[r] = tk1[r];
                        if (s < tv0[r]) { tv1[r] = tv0[r]; tk1[r] = tk0[r]; tv0[r] = s; tk0[r] = k; }
                        else            { tv1[r] = s;      tk1[r] = k; }
                    } else { tv2[r] = s; tk2[r] = k; }
                }
            }
        }

        if (g + 1 < 16) __syncthreads();
        cur ^= 1;
    }

    // ---- part-local rowmin + ballot-compacted candidate (k, score) write ----
    const int grpShift = (l >> 4) * 16;
    const unsigned laneMask = (1u << (l & 15)) - 1u;
#pragma unroll
    for (int r = 0; r < 4; ++r) {
        float v = tv0[r];
#pragma unroll
        for (int m = 1; m <= 8; m <<= 1) v = fminf(v, __shfl_xor(v, m));
        const float thr = v + MARGIN;
        const int row = r0 + ((l >> 4) << 2) + r;
        int* creg = cand + ((size_t)row * 2 + p) * 16;
        int base = 0;
        {
            bool c = tv0[r] <= thr;
            unsigned long long bal = __ballot(c);
            unsigned grp = (unsigned)(bal >> grpShift) & 0xFFFFu;
            int pos = base + __popc(grp & laneMask);
            if (c && pos < 7) { creg[1 + pos] = tk0[r]; creg[8 + pos] = __float_as_int(tv0[r]); }
            base += __popc(grp);
        }
        {
            bool c = tv1[r] <= thr;
            unsigned long long bal = __ballot(c);
            unsigned grp = (unsigned)(bal >> grpShift) & 0xFFFFu;
            int pos = base + __popc(grp & laneMask);
            if (c && pos < 7) { creg[1 + pos] = tk1[r]; creg[8 + pos] = __float_as_int(tv1[r]); }
            base += __popc(grp);
        }
        {
            bool c = tv2[r] <= thr;
            unsigned long long bal = __ballot(c);
            unsigned grp = (unsigned)(bal >> grpShift) & 0xFFFFu;
            int pos = base + __popc(grp & laneMask);
            if (c && pos < 7) { creg[1 + pos] = tk2[r]; creg[8 + pos] = __float_as_int(tv2[r]); }
            base += __popc(grp);
        }
        if ((l & 15) == 0) creg[0] = base < 7 ? base : 7;
    }

    // ---- ticket: second finisher of this rowtile merges + runs epilogue ----
    __threadfence();                 // release: this block's cand stores visible device-wide
    __syncthreads();
    if (t == 0) sh_tick = atomicAdd(&ticket[rt], 1);
    __syncthreads();
    if (sh_tick != 1) return;        // first finisher exits; second merges
    __threadfence();                 // acquire: see the other part's cand

    double ls0 = 0.0, ls1 = 0.0, ls2 = 0.0, ls3 = 0.0;
    for (int rr = 0; rr < 16; ++rr) {
        const int row = rt * 64 + wv * 16 + rr;
        const float4 xv = ((const float4*)(x + (size_t)row * DIM))[l];
        const int* c0 = cand + (size_t)row * 32;

        float m = FLT_MAX;
#pragma unroll
        for (int p2 = 0; p2 < 2; ++p2) {
            const int* cp = c0 + p2 * 16;
            const int n = cp[0];
            for (int c = 0; c < n; ++c) m = fminf(m, __int_as_float(cp[8 + c]));
        }
        const float thr = m + MARGIN;

        int bk = 0x7FFFFFFF, cnt = 0;
#pragma unroll
        for (int p2 = 0; p2 < 2; ++p2) {
            const int* cp = c0 + p2 * 16;
            const int n = cp[0];
            for (int c = 0; c < n; ++c)
                if (__int_as_float(cp[8 + c]) <= thr) { ++cnt; bk = cp[1 + c]; }
        }
        if (cnt > 1) {
            double best = 1e300; bk = 0x7FFFFFFF;
#pragma unroll
            for (int p2 = 0; p2 < 2; ++p2) {
                const int* cp = c0 + p2 * 16;
                const int n = cp[0];
                for (int c = 0; c < n; ++c) {
                    if (__int_as_float(cp[8 + c]) > thr) continue;
                    const int k2 = cp[1 + c];
                    const float4 w4 = ((const float4*)(wT + (size_t)k2 * DIM))[l];
                    double d = (double)xv.x * (double)w4.x;
                    d = fma((double)xv.y, (double)w4.y, d);
                    d = fma((double)xv.z, (double)w4.z, d);
                    d = fma((double)xv.w, (double)w4.w, d);
#pragma unroll
                    for (int mm = 32; mm > 0; mm >>= 1) d += __shfl_xor(d, mm);
                    const double s64 = wnorm64[k2] - 2.0 * d;
                    if (s64 < best || (s64 == best && k2 < bk)) { best = s64; bk = k2; }
                }
            }
        }
        const int k = __builtin_amdgcn_readfirstlane(bk);

        const float4 qv = ((const float4*)(wT + (size_t)k * DIM))[l];
        f32x4 o = {xv.x + (qv.x - xv.x), xv.y + (qv.y - xv.y),
                   xv.z + (qv.z - xv.z), xv.w + (qv.w - xv.w)};
        __builtin_nontemporal_store(o, (f32x4*)(out_q + (size_t)row * DIM) + l);
        double dx = (double)qv.x - (double)xv.x; ls0 = fma(dx, dx, ls0);
        dx = (double)qv.y - (double)xv.y; ls1 = fma(dx, dx, ls1);
        dx = (double)qv.z - (double)xv.z; ls2 = fma(dx, dx, ls2);
        dx = (double)qv.w - (double)xv.w; ls3 = fma(dx, dx, ls3);
        // zeros for this row were written by both parts before their tickets:
        if (l == 0) {
            out_enc[(size_t)row * KC + k] = 1.0f;
            out_idx[row] = (float)k;
            atomicAdd(&counts[k], 1);
        }
    }
    double lsum = (ls0 + ls1) + (ls2 + ls3);
#pragma unroll
    for (int off = 32; off > 0; off >>= 1) lsum += __shfl_down(lsum, off);
    if (l == 0) wsum[wv] = lsum;
    __syncthreads();
    if (t == 0) atomicAdd(loss_sum, wsum[0] + wsum[1] + wsum[2] + wsum[3]);
}

// ---------- finalize ----------
__global__ __launch_bounds__(1024) void final_kernel(const int* __restrict__ counts,
                                                     const double* __restrict__ loss_sum,
                                                     float* __restrict__ out_loss,
                                                     float* __restrict__ out_ppl) {
    const int t = threadIdx.x;
    double p = (double)counts[t] * (1.0 / 32768.0);
    double term = -p * log(p + 1e-10);
#pragma unroll
    for (int off = 32; off > 0; off >>= 1) term += __shfl_down(term, off);
    __shared__ double ws[16];
    if ((t & 63) == 0) ws[t >> 6] = term;
    __syncthreads();
    if (t == 0) {
        double s = 0.0;
        for (int i = 0; i < 16; ++i) s += ws[i];
        *out_ppl = (float)exp(s);
        *out_loss = (float)(1.25 * loss_sum[0] * (1.0 / 8388608.0));
    }
}

extern "C" void kernel_launch(void* const* d_in, const int* in_sizes, int n_in,
                              void* d_out, int out_size, void* d_ws, size_t ws_size,
                              hipStream_t stream) {
    const float* x = (const float*)d_in[0];   // [32,32,32,256] fp32
    const float* w = (const float*)d_in[1];   // [256,1024] fp32

    float* out = (float*)d_out;
    float* out_q    = out;                        // 8388608
    float* out_loss = out + 8388608;              // 1
    float* out_ppl  = out + 8388609;              // 1
    float* out_enc  = out + 8388610;              // 33554432
    float* out_idx  = out + 8388610 + 33554432;   // 32768

    char* wsb = (char*)d_ws;
    double* loss_sum = (double*)(wsb + 0);        // 8 B
    int*    counts   = (int*)(wsb + 64);          // 4096 B -> ends 4160
    int*    ticket   = (int*)(wsb + 4160);        // 2048 B -> ends 6208
    double* wnorm64  = (double*)(wsb + 6208);     // 8192 B -> ends 14400
    float*  wnormf   = (float*)(wsb + 14400);     // 4096 B -> ends 18496
    float*  wT       = (float*)(wsb + 18496);     // 1 MB   -> ends 1067072
    uint4*  wph      = (uint4*)(wsb + 1067072);   // 512 KB -> ends 1591360
    int*    cand     = (int*)(wsb + 1591360);     // 4 MB candidate lists

    (void)hipMemsetAsync(d_ws, 0, 6208, stream);  // loss_sum + counts + ticket

    prep_wnorm<<<64, 512, 0, stream>>>(w, wph, wT, wnorm64, wnormf);
    vq_fused<<<1024, 256, 0, stream>>>(x, (const char*)wph, wT, wnorm64, wnormf,
                                       cand, ticket,
                                       out_q, out_idx, out_enc, counts, loss_sum);
    final_kernel<<<1, 1024, 0, stream>>>(counts, loss_sum, out_loss, out_ppl);
}

// Round 20
// 124.658 us; speedup vs baseline: 2.8997x; 2.8997x over previous
//
#include <hip/hip_runtime.h>
#include <cfloat>
#include <cmath>
#include <stdint.h>

#define NROWS 32768
#define DIM   256
#define KC    1024
#define MARGIN 0.125f

typedef short bf16x8 __attribute__((ext_vector_type(8)));
typedef float f32x4  __attribute__((ext_vector_type(4)));
typedef float f32x2  __attribute__((ext_vector_type(2)));

__device__ inline unsigned short f2bf(float f) {
    unsigned u = __float_as_uint(f);
    u = (u + 0x7fffu + ((u >> 16) & 1u)) >> 16;   // RNE
    return (unsigned short)u;
}

// ---------- prep_wnorm: pack w (hi bf16) + transpose + column norms ----------
// 64 blocks x 512 threads, one 16-col group (ctg) per block. (proven in R19)
__global__ __launch_bounds__(512) void prep_wnorm(const float* __restrict__ w,
                                                  uint4* __restrict__ wph,
                                                  float* __restrict__ wT,
                                                  double* __restrict__ wnorm64,
                                                  float* __restrict__ wnormf) {
    const int tl = threadIdx.x;
    const int ctg = blockIdx.x;
    const int t = ctg * 512 + tl;
    const int l = tl & 63;
    const int ks = (tl >> 6) & 7;
    const int c = ctg * 16 + (l & 15);
    const int kbase = ks * 32 + ((l >> 4) << 3);
    union { unsigned short u[8]; uint4 v; } H;
    double s = 0.0;
#pragma unroll
    for (int j = 0; j < 8; ++j) {
        float v = w[(size_t)(kbase + j) * KC + c];
        H.u[j] = f2bf(v);
        wT[(size_t)c * DIM + kbase + j] = v;
        s = fma((double)v, (double)v, s);
    }
    wph[t] = H.v;
    s += __shfl_xor(s, 16);
    s += __shfl_xor(s, 32);
    __shared__ double part[8][16];
    if (l < 16) part[ks][l] = s;
    __syncthreads();
    if (tl < 16) {
        double tot = 0.0;
#pragma unroll
        for (int i = 0; i < 8; ++i) tot += part[i][tl];
        wnorm64[ctg * 16 + tl] = tot;
        wnormf[ctg * 16 + tl] = (float)tot;
    }
}

// ---------- kernel A: bf16 screen v10 — 512-thr blocks, B fan-out halved ----------
// block = (rowtile rt = bid>>1 [128 rows, 8 waves], part p = bid&1 [512 cols]).
// Same R16 structure: 16 staging groups of 32 cols (16KB), 2x16KB LDS dbuf.
// 512 blocks x 512 thr -> 2 blocks/CU, 16 waves/CU (same as R16) but HALF the
// blocks reading B: L2 fan-out 256 -> 128 MB. Zero-fill in load-stall shadow.
// cand entry per (row,part): 16 ints = [n, k0..k6, s0..s6(bits), pad]
__global__ __launch_bounds__(512, 4) void vq_screen(
    const float* __restrict__ x,
    const char* __restrict__ wph,
    const float* __restrict__ wnormf,
    int* __restrict__ cand,
    float* __restrict__ out_enc)
{
    __shared__ char ldsbuf[32768];

    const int t = threadIdx.x;
    const int l = t & 63;
    const int wv = t >> 6;                      // 0..7
    const int p = blockIdx.x & 1;
    const int rt = blockIdx.x >> 1;
    const int r0 = rt * 128 + wv * 16;
    const size_t pbase = (size_t)p * 262144;    // part offset into wph (bytes)

    // ---- A fragments: 16 rows x 256 k, hi bf16 ----
    bf16x8 ah[8];
    {
        const float* xb = x + (size_t)(r0 + (l & 15)) * DIM + ((l >> 4) << 3);
#pragma unroll
        for (int ks = 0; ks < 8; ++ks) {
            float4 p0 = *(const float4*)(xb + ks * 32);
            float4 p1 = *(const float4*)(xb + ks * 32 + 4);
            float f[8] = {p0.x, p0.y, p0.z, p0.w, p1.x, p1.y, p1.z, p1.w};
            union { unsigned short u[8]; bf16x8 v; } H;
#pragma unroll
            for (int j = 0; j < 8; ++j) H.u[j] = f2bf(f[j]);
            ah[ks] = H.v;
        }
    }

    float tv0[4], tv1[4], tv2[4];
    int   tk0[4], tk1[4], tk2[4];
#pragma unroll
    for (int r = 0; r < 4; ++r) { tv0[r] = tv1[r] = tv2[r] = FLT_MAX; tk0[r] = tk1[r] = tk2[r] = 0; }

    // ---- K-loop: 16 groups of 32 cols, double-buffered; 2 loads/thread ----
    {
        const char* g0 = wph + pbase + wv * 1024 + l * 16;
        char* lp0 = ldsbuf + wv * 1024 + l * 16;
#pragma unroll
        for (int i = 0; i < 2; ++i)
            __builtin_amdgcn_global_load_lds(
                (const __attribute__((address_space(1))) void*)(g0 + i * 8192),
                (__attribute__((address_space(3))) void*)(lp0 + i * 8192), 16, 0, 0);
    }
    __syncthreads();

    int cur = 0;
    for (int g = 0; g < 16; ++g) {
        if (g + 1 < 16) {
            const char* gp = wph + pbase + (size_t)(g + 1) * 16384 + wv * 1024 + l * 16;
            char* lp = ldsbuf + (cur ^ 1) * 16384 + wv * 1024 + l * 16;
#pragma unroll
            for (int i = 0; i < 2; ++i)
                __builtin_amdgcn_global_load_lds(
                    (const __attribute__((address_space(1))) void*)(gp + i * 8192),
                    (__attribute__((address_space(3))) void*)(lp + i * 8192), 16, 0, 0);
        }

        // enc zero-fill in the load-stall shadow: one row x 512 cols per wave per iter
        {
            const int zrow = r0 + g;
            f32x2* er2 = (f32x2*)(out_enc + (size_t)zrow * KC + p * 512);
            f32x2 z = {0.f, 0.f};
#pragma unroll
            for (int i = 0; i < 4; ++i)
                __builtin_nontemporal_store(z, er2 + i * 64 + l);
        }

        f32x4 acc[2];
#pragma unroll
        for (int ct = 0; ct < 2; ++ct) acc[ct] = (f32x4){0.f, 0.f, 0.f, 0.f};

#pragma unroll
        for (int ks = 0; ks < 8; ++ks) {
#pragma unroll
            for (int ct = 0; ct < 2; ++ct) {
                bf16x8 bh = *(const bf16x8*)(ldsbuf + cur * 16384 + ((ct * 8 + ks) * 64 + l) * 16);
                acc[ct] = __builtin_amdgcn_mfma_f32_16x16x32_bf16(ah[ks], bh, acc[ct], 0, 0, 0);
            }
        }

#pragma unroll
        for (int ct = 0; ct < 2; ++ct) {
            const int k = (p * 32 + g * 2 + ct) * 16 + (l & 15);
            const float wn = wnormf[k];
#pragma unroll
            for (int r = 0; r < 4; ++r) {
                float s = wn - 2.0f * acc[ct][r];
                if (s < tv2[r]) {
                    if (s < tv1[r]) {
                        tv2[r] = tv1[r]; tk2[r] = tk1[r];
                        if (s < tv0[r]) { tv1[r] = tv0[r]; tk1[r] = tk0[r]; tv0[r] = s; tk0[r] = k; }
                        else            { tv1[r] = s;      tk1[r] = k; }
                    } else { tv2[r] = s; tk2[r] = k; }
                }
            }
        }

        if (g + 1 < 16) __syncthreads();
        cur ^= 1;
    }

    // ---- part-local rowmin + ballot-compacted candidate (k, score) write ----
    const int grpShift = (l >> 4) * 16;
    const unsigned laneMask = (1u << (l & 15)) - 1u;
#pragma unroll
    for (int r = 0; r < 4; ++r) {
        float v = tv0[r];
#pragma unroll
        for (int m = 1; m <= 8; m <<= 1) v = fminf(v, __shfl_xor(v, m));
        const float thr = v + MARGIN;
        const int row = r0 + ((l >> 4) << 2) + r;
        int* creg = cand + ((size_t)row * 2 + p) * 16;
        int base = 0;
        {
            bool c = tv0[r] <= thr;
            unsigned long long bal = __ballot(c);
            unsigned grp = (unsigned)(bal >> grpShift) & 0xFFFFu;
            int pos = base + __popc(grp & laneMask);
            if (c && pos < 7) { creg[1 + pos] = tk0[r]; creg[8 + pos] = __float_as_int(tv0[r]); }
            base += __popc(grp);
        }
        {
            bool c = tv1[r] <= thr;
            unsigned long long bal = __ballot(c);
            unsigned grp = (unsigned)(bal >> grpShift) & 0xFFFFu;
            int pos = base + __popc(grp & laneMask);
            if (c && pos < 7) { creg[1 + pos] = tk1[r]; creg[8 + pos] = __float_as_int(tv1[r]); }
            base += __popc(grp);
        }
        {
            bool c = tv2[r] <= thr;
            unsigned long long bal = __ballot(c);
            unsigned grp = (unsigned)(bal >> grpShift) & 0xFFFFu;
            int pos = base + __popc(grp & laneMask);
            if (c && pos < 7) { creg[1 + pos] = tk2[r]; creg[8 + pos] = __float_as_int(tv2[r]); }
            base += __popc(grp);
        }
        if ((l & 15) == 0) creg[0] = base < 7 ? base : 7;
    }
}

// ---------- kernel B: slim select + rare fp64 refine + epilogue (R16 verbatim) ----------
__global__ __launch_bounds__(256) void vq_final(
    const float* __restrict__ x, const float* __restrict__ wT,
    const double* __restrict__ wnorm64,
    const int* __restrict__ cand,
    float* __restrict__ out_q, float* __restrict__ out_idx, float* __restrict__ out_enc,
    int* __restrict__ counts, double* __restrict__ loss_sum)
{
    const int t = threadIdx.x;
    const int l = t & 63;
    const int wv = t >> 6;
    __shared__ double wsum[4];

    double ls0 = 0.0, ls1 = 0.0, ls2 = 0.0, ls3 = 0.0;
    const int stride = gridDim.x * 4;
    for (int row = blockIdx.x * 4 + wv; row < NROWS; row += stride) {
        const float4 xv = ((const float4*)(x + (size_t)row * DIM))[l];
        const int* c0 = cand + (size_t)row * 32;

        float m = FLT_MAX;
#pragma unroll
        for (int p2 = 0; p2 < 2; ++p2) {
            const int* cp = c0 + p2 * 16;
            const int n = cp[0];
            for (int c = 0; c < n; ++c) m = fminf(m, __int_as_float(cp[8 + c]));
        }
        const float thr = m + MARGIN;

        int bk = 0x7FFFFFFF, cnt = 0;
#pragma unroll
        for (int p2 = 0; p2 < 2; ++p2) {
            const int* cp = c0 + p2 * 16;
            const int n = cp[0];
            for (int c = 0; c < n; ++c)
                if (__int_as_float(cp[8 + c]) <= thr) { ++cnt; bk = cp[1 + c]; }
        }
        if (cnt > 1) {
            double best = 1e300; bk = 0x7FFFFFFF;
#pragma unroll
            for (int p2 = 0; p2 < 2; ++p2) {
                const int* cp = c0 + p2 * 16;
                const int n = cp[0];
                for (int c = 0; c < n; ++c) {
                    if (__int_as_float(cp[8 + c]) > thr) continue;
                    const int k2 = cp[1 + c];
                    const float4 w4 = ((const float4*)(wT + (size_t)k2 * DIM))[l];
                    double d = (double)xv.x * (double)w4.x;
                    d = fma((double)xv.y, (double)w4.y, d);
                    d = fma((double)xv.z, (double)w4.z, d);
                    d = fma((double)xv.w, (double)w4.w, d);
#pragma unroll
                    for (int mm = 32; mm > 0; mm >>= 1) d += __shfl_xor(d, mm);
                    const double s64 = wnorm64[k2] - 2.0 * d;
                    if (s64 < best || (s64 == best && k2 < bk)) { best = s64; bk = k2; }
                }
            }
        }
        const int k = __builtin_amdgcn_readfirstlane(bk);

        const float4 qv = ((const float4*)(wT + (size_t)k * DIM))[l];
        f32x4 o = {xv.x + (qv.x - xv.x), xv.y + (qv.y - xv.y),
                   xv.z + (qv.z - xv.z), xv.w + (qv.w - xv.w)};
        __builtin_nontemporal_store(o, (f32x4*)(out_q + (size_t)row * DIM) + l);
        double dx = (double)qv.x - (double)xv.x; ls0 = fma(dx, dx, ls0);
        dx = (double)qv.y - (double)xv.y; ls1 = fma(dx, dx, ls1);
        dx = (double)qv.z - (double)xv.z; ls2 = fma(dx, dx, ls2);
        dx = (double)qv.w - (double)xv.w; ls3 = fma(dx, dx, ls3);
        if (l == 0) {
            out_enc[(size_t)row * KC + k] = 1.0f;
            out_idx[row] = (float)k;
            atomicAdd(&counts[k], 1);
        }
    }
    double lsum = (ls0 + ls1) + (ls2 + ls3);
#pragma unroll
    for (int off = 32; off > 0; off >>= 1) lsum += __shfl_down(lsum, off);
    if (l == 0) wsum[wv] = lsum;
    __syncthreads();
    if (t == 0) atomicAdd(loss_sum, wsum[0] + wsum[1] + wsum[2] + wsum[3]);
}

// ---------- finalize ----------
__global__ __launch_bounds__(1024) void final_kernel(const int* __restrict__ counts,
                                                     const double* __restrict__ loss_sum,
                                                     float* __restrict__ out_loss,
                                                     float* __restrict__ out_ppl) {
    const int t = threadIdx.x;
    double p = (double)counts[t] * (1.0 / 32768.0);
    double term = -p * log(p + 1e-10);
#pragma unroll
    for (int off = 32; off > 0; off >>= 1) term += __shfl_down(term, off);
    __shared__ double ws[16];
    if ((t & 63) == 0) ws[t >> 6] = term;
    __syncthreads();
    if (t == 0) {
        double s = 0.0;
        for (int i = 0; i < 16; ++i) s += ws[i];
        *out_ppl = (float)exp(s);
        *out_loss = (float)(1.25 * loss_sum[0] * (1.0 / 8388608.0));
    }
}

extern "C" void kernel_launch(void* const* d_in, const int* in_sizes, int n_in,
                              void* d_out, int out_size, void* d_ws, size_t ws_size,
                              hipStream_t stream) {
    const float* x = (const float*)d_in[0];   // [32,32,32,256] fp32
    const float* w = (const float*)d_in[1];   // [256,1024] fp32

    float* out = (float*)d_out;
    float* out_q    = out;                        // 8388608
    float* out_loss = out + 8388608;              // 1
    float* out_ppl  = out + 8388609;              // 1
    float* out_enc  = out + 8388610;              // 33554432
    float* out_idx  = out + 8388610 + 33554432;   // 32768

    char* wsb = (char*)d_ws;
    double* loss_sum = (double*)(wsb + 0);        // 8 B
    int*    counts   = (int*)(wsb + 64);          // 4096 B -> ends 4160
    double* wnorm64  = (double*)(wsb + 4160);     // 8192 B -> ends 12352
    float*  wnormf   = (float*)(wsb + 12352);     // 4096 B -> ends 16448
    float*  wT       = (float*)(wsb + 16448);     // 1 MB   -> ends 1065024
    uint4*  wph      = (uint4*)(wsb + 1065024);   // 512 KB -> ends 1589312
    int*    cand     = (int*)(wsb + 1589312);     // 4 MB candidate lists

    (void)hipMemsetAsync(d_ws, 0, 4160, stream);  // loss_sum + counts

    prep_wnorm<<<64, 512, 0, stream>>>(w, wph, wT, wnorm64, wnormf);
    vq_screen<<<512, 512, 0, stream>>>(x, (const char*)wph, wnormf, cand, out_enc);
    vq_final<<<2048, 256, 0, stream>>>(x, wT, wnorm64, cand,
                                       out_q, out_idx, out_enc, counts, loss_sum);
    final_kernel<<<1, 1024, 0, stream>>>(counts, loss_sum, out_loss, out_ppl);
}